// Round 1
// baseline (3040.350 us; speedup 1.0000x reference)
//
#include <hip/hip_runtime.h>

typedef unsigned short ushort_t;
typedef __bf16 bf16x8 __attribute__((ext_vector_type(8)));
typedef float f32x4 __attribute__((ext_vector_type(4)));

#define PACK_W_ELEMS (8*9*8*512)           // 294912 bf16 per LSTM: [wave8][kt9][gu8][512]
#define HEAD_ELEMS   (9*512)               // 1 n-tile x 9 k-tiles
#define PACK_TOTAL   (4*PACK_W_ELEMS + 2*HEAD_ELEMS)
#define FLAG_OFS     PACK_TOTAL            // ushort index of int dtype flag

__device__ __forceinline__ float bf2f(ushort_t u){ return __uint_as_float(((unsigned)u)<<16); }
__device__ __forceinline__ ushort_t f2bf(float f){
  __bf16 h = (__bf16)f;                    // HW RTNE convert (values bounded)
  return *(ushort_t*)&h;
}
__device__ __forceinline__ float rcp_(float x){ return __builtin_amdgcn_rcpf(x); }
__device__ __forceinline__ float sigmf_(float x){ return rcp_(1.0f + __expf(-x)); }
__device__ __forceinline__ float tanhf_(float x){ return 1.0f - 2.0f*rcp_(1.0f + __expf(2.0f*x)); }

__device__ __forceinline__ int sniff_f32(const ushort_t* w){
  int f32 = 0;
  #pragma unroll
  for (int i = 0; i < 32; ++i){
    float f = bf2f(w[2*i]);
    if (!(f > -8.f && f < 8.f)) f32 = 1;
  }
  return f32;
}
__device__ __forceinline__ float ldin(const ushort_t* p, int i, int f32){
  return f32 ? ((const float*)p)[i] : bf2f(p[i]);
}
__device__ __forceinline__ float ldin_nt(const ushort_t* p, int i, int f32){
  return f32 ? __builtin_nontemporal_load((const float*)p + i)
             : bf2f(__builtin_nontemporal_load(p + i));
}
__device__ __forceinline__ ushort_t ldw(const ushort_t* p, int i, int f32){
  return f32 ? f2bf(((const float*)p)[i]) : p[i];
}

// ---------------- pack kernel (unchanged layout) ----------------
// Per-LSTM pack: [wv(8)][kt(9)][gu(8)][512]; tile (wv,kt,g,u) = B-frag of n-tile
// ntg = g*16 + wv*2 + u.  K map: k<256 Whh, 256..259 Wih, k==260 bias row (bih+bhh), else 0.
struct PackArgs {
  const ushort_t* wih[4]; const ushort_t* whh[4];
  const ushort_t* bih[4]; const ushort_t* bhh[4];
  const ushort_t* fcsp_w; const ushort_t* fcsp_b;
  const ushort_t* fccr_w; const ushort_t* fccr_b;
  const ushort_t* emb_w;  const ushort_t* emb_b;
  ushort_t* ws;
};

__global__ void pack_kernel(PackArgs a){
  const int f32 = sniff_f32(a.whh[0]);
  int idx = blockIdx.x*256 + threadIdx.x;
  if (blockIdx.x == 0 && threadIdx.x == 0) *(int*)(a.ws + FLAG_OFS) = f32;
  const int total_w = 4*PACK_W_ELEMS;
  if (idx < total_w){
    int l = idx / PACK_W_ELEMS;
    int r = idx % PACK_W_ELEMS;
    int j = r & 7;
    int lane = (r>>3) & 63;
    int tile = r >> 9;            // (wv*9 + kt)*8 + gu
    int gu = tile & 7;
    int kt = (tile >> 3) % 9;
    int wv = tile / 72;
    int g = gu >> 1, u = gu & 1;
    int n = (g*16 + wv*2 + u)*16 + (lane & 15);
    int k = kt*32 + ((lane>>4)<<3) + j;
    ushort_t v = 0;
    if (k < 256)       v = ldw(a.whh[l], n*256 + k, f32);
    else if (k < 260)  v = ldw(a.wih[l], n*4 + (k-256), f32);
    else if (k == 260) v = f2bf(ldin(a.bih[l], n, f32) + ldin(a.bhh[l], n, f32));
    a.ws[l*PACK_W_ELEMS + r] = v;
    return;
  }
  idx -= total_w;
  if (idx < 2*HEAD_ELEMS){
    int which = idx / HEAD_ELEMS;           // 0 = speed, 1 = cross
    int r = idx % HEAD_ELEMS;
    int j = r & 7; int lane = (r>>3)&63; int kt = r>>9;
    int n = lane & 15; int k = kt*32 + ((lane>>4)<<3) + j;
    ushort_t v = 0;
    if (which == 0){
      if (n < 4){
        if (k < 256)       v = ldw(a.fcsp_w, n*256 + k, f32);
        else if (k == 260) v = f2bf(ldin(a.fcsp_b, n, f32));
      }
    } else {
      if (n < 4){
        if (k < 256)       v = ldw(a.emb_w, n*256 + k, f32);
        else if (k == 260) v = f2bf(ldin(a.emb_b, n, f32));
      } else if (n < 6){
        if (k < 256)       v = ldw(a.fccr_w, (n-4)*256 + k, f32);
        else if (k == 260) v = f2bf(ldin(a.fccr_b, n-4, f32));
      }
    }
    a.ws[total_w + idx] = v;
  }
}

// ---------------- fused split-gate GEMM + interleaved gate VALU ----------------
// Gate order in acc: gu = gate*2+u, gates {i=0,f=1,g=2,o=3} -> P1 = gu 0..5 (i,f,g),
// P2 = gu 6..7 (o).  Two-region pipeline (per wave, registers only):
//   entering a region: acc[*][6..7] = other-LSTM (Y) o-gates, cwY already cn-updated.
//   P1 (216 MFMAs, writes acc[*][0..5])  || hn_Y = sigm(Y_o)*tanh(cwY) -> ApY  (Y{o} dies)
//   P2 (72 MFMAs, re-uses acc[*][6..7])  || cn_X from final X{i,f,g} -> cwX
// Peak acc = 96+32 = 128 regs (same as before); per-element op order identical ->
// bit-identical numerics vs the unfused version.
template<int HN>
__device__ __forceinline__ void fused_step(
    const ushort_t* __restrict__ Aln,   // A-pack of X + lane*8
    const ushort_t* __restrict__ bw,    // X weight pack + wave/lane offset
    f32x4 (&acc)[4][8],
    float (&cwX)[4][2][4],              // X c-state (updated by cn)
    float (&cwY)[4][2][4],              // Y c-state (read by hn)
    ushort_t* __restrict__ ApY,         // Y A-pack (hn h write-back)
    int wbBase)
{
  // ---------------- P1: gates i,f,g ----------------
  #pragma unroll
  for (int kt = 0; kt < 9; ++kt){
    const ushort_t* bp = bw + kt*4096;
    bf16x8 b0 = *(const bf16x8*)&bp[0*512];
    bf16x8 b1 = *(const bf16x8*)&bp[1*512];
    bf16x8 b2 = *(const bf16x8*)&bp[2*512];
    bf16x8 b3 = *(const bf16x8*)&bp[3*512];
    bf16x8 b4 = *(const bf16x8*)&bp[4*512];
    bf16x8 b5 = *(const bf16x8*)&bp[5*512];
    bf16x8 a0 = *(const bf16x8*)&Aln[(0*9+kt)*512];
    bf16x8 a1 = *(const bf16x8*)&Aln[(1*9+kt)*512];
    bf16x8 a2 = *(const bf16x8*)&Aln[(2*9+kt)*512];
    bf16x8 a3 = *(const bf16x8*)&Aln[(3*9+kt)*512];
    if (kt == 0){
      #pragma unroll
      for (int i = 0; i < 4; ++i)
        #pragma unroll
        for (int j = 0; j < 6; ++j) acc[i][j] = (f32x4){0.f,0.f,0.f,0.f};
    }
    acc[0][0] = __builtin_amdgcn_mfma_f32_16x16x32_bf16(a0, b0, acc[0][0], 0, 0, 0);
    acc[1][0] = __builtin_amdgcn_mfma_f32_16x16x32_bf16(a1, b0, acc[1][0], 0, 0, 0);
    acc[2][0] = __builtin_amdgcn_mfma_f32_16x16x32_bf16(a2, b0, acc[2][0], 0, 0, 0);
    acc[3][0] = __builtin_amdgcn_mfma_f32_16x16x32_bf16(a3, b0, acc[3][0], 0, 0, 0);
    acc[0][1] = __builtin_amdgcn_mfma_f32_16x16x32_bf16(a0, b1, acc[0][1], 0, 0, 0);
    acc[1][1] = __builtin_amdgcn_mfma_f32_16x16x32_bf16(a1, b1, acc[1][1], 0, 0, 0);
    acc[2][1] = __builtin_amdgcn_mfma_f32_16x16x32_bf16(a2, b1, acc[2][1], 0, 0, 0);
    acc[3][1] = __builtin_amdgcn_mfma_f32_16x16x32_bf16(a3, b1, acc[3][1], 0, 0, 0);
    acc[0][2] = __builtin_amdgcn_mfma_f32_16x16x32_bf16(a0, b2, acc[0][2], 0, 0, 0);
    acc[1][2] = __builtin_amdgcn_mfma_f32_16x16x32_bf16(a1, b2, acc[1][2], 0, 0, 0);
    acc[2][2] = __builtin_amdgcn_mfma_f32_16x16x32_bf16(a2, b2, acc[2][2], 0, 0, 0);
    acc[3][2] = __builtin_amdgcn_mfma_f32_16x16x32_bf16(a3, b2, acc[3][2], 0, 0, 0);
    acc[0][3] = __builtin_amdgcn_mfma_f32_16x16x32_bf16(a0, b3, acc[0][3], 0, 0, 0);
    acc[1][3] = __builtin_amdgcn_mfma_f32_16x16x32_bf16(a1, b3, acc[1][3], 0, 0, 0);
    acc[2][3] = __builtin_amdgcn_mfma_f32_16x16x32_bf16(a2, b3, acc[2][3], 0, 0, 0);
    acc[3][3] = __builtin_amdgcn_mfma_f32_16x16x32_bf16(a3, b3, acc[3][3], 0, 0, 0);
    acc[0][4] = __builtin_amdgcn_mfma_f32_16x16x32_bf16(a0, b4, acc[0][4], 0, 0, 0);
    acc[1][4] = __builtin_amdgcn_mfma_f32_16x16x32_bf16(a1, b4, acc[1][4], 0, 0, 0);
    acc[2][4] = __builtin_amdgcn_mfma_f32_16x16x32_bf16(a2, b4, acc[2][4], 0, 0, 0);
    acc[3][4] = __builtin_amdgcn_mfma_f32_16x16x32_bf16(a3, b4, acc[3][4], 0, 0, 0);
    acc[0][5] = __builtin_amdgcn_mfma_f32_16x16x32_bf16(a0, b5, acc[0][5], 0, 0, 0);
    acc[1][5] = __builtin_amdgcn_mfma_f32_16x16x32_bf16(a1, b5, acc[1][5], 0, 0, 0);
    acc[2][5] = __builtin_amdgcn_mfma_f32_16x16x32_bf16(a2, b5, acc[2][5], 0, 0, 0);
    acc[3][5] = __builtin_amdgcn_mfma_f32_16x16x32_bf16(a3, b5, acc[3][5], 0, 0, 0);
    // hn of the OTHER LSTM: reads acc[*][6..7] (its o-gates) + cwY; independent of P1.
    if (HN && kt >= 1){
      #pragma unroll
      for (int ee = 0; ee < 4; ++ee){
        const int e  = (kt-1)*4 + ee;              // 0..31 across kt=1..8
        const int mt = e >> 3, u = (e >> 2) & 1, r = e & 3;
        const float hn = sigmf_(acc[mt][6+u][r]) * tanhf_(cwY[mt][u][r]);
        ApY[mt*4608 + u*256 + r*8 + wbBase] = f2bf(hn);
      }
    }
  }
  // ---------------- P2: gate o ----------------
  #pragma unroll
  for (int kt = 0; kt < 9; ++kt){
    const ushort_t* bp = bw + kt*4096;
    bf16x8 b6 = *(const bf16x8*)&bp[6*512];
    bf16x8 b7 = *(const bf16x8*)&bp[7*512];
    bf16x8 a0 = *(const bf16x8*)&Aln[(0*9+kt)*512];
    bf16x8 a1 = *(const bf16x8*)&Aln[(1*9+kt)*512];
    bf16x8 a2 = *(const bf16x8*)&Aln[(2*9+kt)*512];
    bf16x8 a3 = *(const bf16x8*)&Aln[(3*9+kt)*512];
    if (kt == 0){
      #pragma unroll
      for (int i = 0; i < 4; ++i){
        acc[i][6] = (f32x4){0.f,0.f,0.f,0.f};
        acc[i][7] = (f32x4){0.f,0.f,0.f,0.f};
      }
    }
    acc[0][6] = __builtin_amdgcn_mfma_f32_16x16x32_bf16(a0, b6, acc[0][6], 0, 0, 0);
    acc[1][6] = __builtin_amdgcn_mfma_f32_16x16x32_bf16(a1, b6, acc[1][6], 0, 0, 0);
    acc[2][6] = __builtin_amdgcn_mfma_f32_16x16x32_bf16(a2, b6, acc[2][6], 0, 0, 0);
    acc[3][6] = __builtin_amdgcn_mfma_f32_16x16x32_bf16(a3, b6, acc[3][6], 0, 0, 0);
    acc[0][7] = __builtin_amdgcn_mfma_f32_16x16x32_bf16(a0, b7, acc[0][7], 0, 0, 0);
    acc[1][7] = __builtin_amdgcn_mfma_f32_16x16x32_bf16(a1, b7, acc[1][7], 0, 0, 0);
    acc[2][7] = __builtin_amdgcn_mfma_f32_16x16x32_bf16(a2, b7, acc[2][7], 0, 0, 0);
    acc[3][7] = __builtin_amdgcn_mfma_f32_16x16x32_bf16(a3, b7, acc[3][7], 0, 0, 0);
    // cn of THIS LSTM: reads final acc[*][0..5] (done after P1); independent of P2.
    if (kt < 8){
      #pragma unroll
      for (int ee = 0; ee < 4; ++ee){
        const int e  = kt*4 + ee;                  // 0..31 across kt=0..7
        const int mt = e >> 3, u = (e >> 2) & 1, r = e & 3;
        const float cn = sigmf_(acc[mt][2+u][r]) * cwX[mt][u][r]
                       + sigmf_(acc[mt][u][r])   * tanhf_(acc[mt][4+u][r]);
        cwX[mt][u][r] = cn;
      }
    }
  }
}

// ---------------- main kernel: 256 blocks x 64 rows, 512 threads (8 waves) ----------------
__global__ __launch_bounds__(512, 2) void pvlstm_main(
    const ushort_t* __restrict__ ws,
    const ushort_t* __restrict__ speed,
    const ushort_t* __restrict__ pos,
    void* __restrict__ outv)
{
  __shared__ ushort_t ApS[4*9*512];   // A-pack speed-enc / speed-dec (36 KB)
  __shared__ ushort_t ApP[4*9*512];   // A-pack pos-enc / cross-dec   (36 KB)
  __shared__ ushort_t xsS[64*64];     // staged speed inputs (8 KB)
  __shared__ ushort_t xsP[64*64];     // staged pos inputs   (8 KB)
  __shared__ float    ostS[64*64];    // speed outputs stage (16 KB)
  __shared__ float    ostC[64*32];    // crossing outputs stage (8 KB)

  const int f32   = *(const int*)(ws + FLAG_OFS);
  const int tid   = threadIdx.x;
  const int lane  = tid & 63;
  const int w     = tid >> 6;   // 0..7
  const int col16 = lane & 15;
  const int quad  = lane >> 4;
  const int brow0 = blockIdx.x * 64;
  const int wbBase = w*512 + (col16>>3)*128 + quad*32 + (col16&7);

  ushort_t* outu = (ushort_t*)outv;
  float*    outf = (float*)outv;

  const ushort_t* headsp = ws + 4*PACK_W_ELEMS;
  const ushort_t* headcr = headsp + HEAD_ELEMS;
  const ushort_t* aS  = ApS + lane*8;
  const ushort_t* aP  = ApP + lane*8;
  const ushort_t* bwS  = ws + 0*PACK_W_ELEMS + (size_t)w*36864 + (size_t)lane*8;
  const ushort_t* bwP  = ws + 1*PACK_W_ELEMS + (size_t)w*36864 + (size_t)lane*8;
  const ushort_t* bwDS = ws + 2*PACK_W_ELEMS + (size_t)w*36864 + (size_t)lane*8;
  const ushort_t* bwDC = ws + 3*PACK_W_ELEMS + (size_t)w*36864 + (size_t)lane*8;

  float cwA[4][2][4], cwB[4][2][4];
  f32x4 acc[4][8];

  // ---- prologue: stage inputs (non-temporal: keep L2 for weights), zero A-packs ----
  for (int i = tid; i < 4096; i += 512){
    int gi = (brow0 + (i>>6))*64 + (i&63);
    xsS[i] = f2bf(ldin_nt(speed, gi, f32));
    xsP[i] = f2bf(ldin_nt(pos,   gi, f32));
  }
  for (int i = tid; i < 4*9*512/2; i += 512){
    ((unsigned*)ApS)[i] = 0u; ((unsigned*)ApP)[i] = 0u;
  }
  #pragma unroll
  for (int mt = 0; mt < 4; ++mt)
    #pragma unroll
    for (int u = 0; u < 2; ++u)
      #pragma unroll
      for (int r = 0; r < 4; ++r){ cwA[mt][u][r] = 0.f; cwB[mt][u][r] = 0.f; }
  __syncthreads();
  if (tid < 64){
    ushort_t* xpS = &ApS[((tid>>4)*9 + 8)*512 + (tid&15)*8];
    ushort_t* xpP = &ApP[((tid>>4)*9 + 8)*512 + (tid&15)*8];
    *(uint2*)xpS = *(const uint2*)&xsS[tid*64];    // x_sp(0)
    xpS[4] = (ushort_t)0x3f80;                     // bias 1.0 column
    xpP[4] = (ushort_t)0x3f80;
  }
  __syncthreads();

  // ================= encoders: sp (A) and po (B), fused pipeline =================
  for (int t = 0; t < 16; ++t){
    // R1: gemm_sp(t) [P1 || hn_po(t-1) -> ApP ; P2 || cn_sp(t)] ; x_po(t) -> ApP.kt8
    if (tid < 64)
      *(uint2*)&ApP[((tid>>4)*9 + 8)*512 + (tid&15)*8] = *(const uint2*)&xsP[tid*64 + t*4];
    if (t > 0) fused_step<1>(aS, bwS, acc, cwA, cwB, ApP, wbBase);
    else       fused_step<0>(aS, bwS, acc, cwA, cwB, ApP, wbBase);
    __syncthreads();
    // R2: gemm_po(t) [P1 || hn_sp(t) -> ApS ; P2 || cn_po(t)] ; x_sp(t+1) -> ApS.kt8
    if (t < 15 && tid < 64)
      *(uint2*)&ApS[((tid>>4)*9 + 8)*512 + (tid&15)*8] = *(const uint2*)&xsS[tid*64 + t*4 + 4];
    fused_step<1>(aP, bwP, acc, cwB, cwA, ApS, wbBase);
    __syncthreads();
  }
  // ---- encoder epilogue: hn_po(15); h0 = h_sp+h_po into BOTH packs; c0 in regs ----
  // (cwB already holds cn_po(15) from R2(15)'s P2; acc[*][6..7] = po(15) o-gates)
  #pragma unroll
  for (int mt = 0; mt < 4; ++mt)
    #pragma unroll
    for (int u = 0; u < 2; ++u)
      #pragma unroll
      for (int r = 0; r < 4; ++r){
        float hn = sigmf_(acc[mt][6+u][r]) * tanhf_(cwB[mt][u][r]);
        float c0 = cwA[mt][u][r] + cwB[mt][u][r];
        cwA[mt][u][r] = c0; cwB[mt][u][r] = c0;
        const int ad = mt*4608 + u*256 + r*8 + wbBase;
        ushort_t h0 = f2bf(bf2f(ApS[ad]) + hn);    // h_sp(15) written in R2(15)'s P1
        ApS[ad] = h0; ApP[ad] = h0;
      }
  if (tid < 64){
    *(uint2*)&ApS[((tid>>4)*9 + 8)*512 + (tid&15)*8] = *(const uint2*)&xsS[tid*64 + 60];  // x0 sp
    *(uint2*)&ApP[((tid>>4)*9 + 8)*512 + (tid&15)*8] = *(const uint2*)&xsP[tid*64 + 60];  // x0 po
  }
  __syncthreads();

  // ================= decoders: dsp (A, ApS) and dcr (B, ApP), fused pipeline =================
  for (int t = 0; t < 16; ++t){
    // R1: head_cr(t-1) [waves 4..7] -> ostC + x_cr(t) ; gemm_dsp(t) [P2 || cn_dsp(t)]
    if (t > 0 && w >= 4){
      const int mt = w - 4;
      f32x4 hacc = (f32x4){0.f,0.f,0.f,0.f};
      #pragma unroll
      for (int kt = 0; kt < 9; ++kt){
        bf16x8 a  = *(const bf16x8*)&aP[(mt*9+kt)*512];
        bf16x8 bv = *(const bf16x8*)&headcr[((size_t)kt*64 + lane)*8];
        hacc = __builtin_amdgcn_mfma_f32_16x16x32_bf16(a, bv, hacc, 0, 0, 0);
      }
      const int s = col16;
      #pragma unroll
      for (int r = 0; r < 4; ++r){
        float v = fmaxf(hacc[r], 0.f);             // relu
        const float o = __shfl_xor(v, 1, 64);      // pair logits (lanes 4<->5)
        const int m = mt*16 + quad*4 + r;
        if (s < 4){
          ApP[(mt*9+8)*512 + (m&15)*8 + s] = f2bf(v);          // x_cr(t) feedback
        } else if (s < 6){
          const float mx = fmaxf(v, o);
          const float e0 = __expf(v-mx), e1 = __expf(o-mx);
          ostC[m*32 + (t-1)*2 + (s-4)] = e0*rcp_(e0+e1);       // softmax2 at t-1
        }
      }
    }
    fused_step<0>(aS, bwDS, acc, cwA, cwB, ApP, wbBase);   // hn_dcr(t-1) was done in R3(t-1)
    __syncthreads();
    // R2: gemm_dcr(t) [P1 || hn_dsp(t) -> ApS ; P2 || cn_dcr(t)]
    fused_step<1>(aP, bwDC, acc, cwB, cwA, ApS, wbBase);
    __syncthreads();
    // R3: hn_dcr(t) -> ApP ; head_sp(t) [waves 0..3] -> ostS + x_sp(t+1)
    #pragma unroll
    for (int mt = 0; mt < 4; ++mt)
      #pragma unroll
      for (int u = 0; u < 2; ++u)
        #pragma unroll
        for (int r = 0; r < 4; ++r){
          const float hn = sigmf_(acc[mt][6+u][r]) * tanhf_(cwB[mt][u][r]);
          ApP[mt*4608 + u*256 + r*8 + wbBase] = f2bf(hn);
        }
    if (w < 4){
      const int mt = w;
      f32x4 hacc = (f32x4){0.f,0.f,0.f,0.f};
      #pragma unroll
      for (int kt = 0; kt < 9; ++kt){
        bf16x8 a  = *(const bf16x8*)&aS[(mt*9+kt)*512];
        bf16x8 bv = *(const bf16x8*)&headsp[((size_t)kt*64 + lane)*8];
        hacc = __builtin_amdgcn_mfma_f32_16x16x32_bf16(a, bv, hacc, 0, 0, 0);
      }
      const int s = col16;
      if (s < 4){
        #pragma unroll
        for (int r = 0; r < 4; ++r){
          float v = fminf(fmaxf(hacc[r], -100.f), 100.f);      // hardtanh(+-100)
          const int m = mt*16 + quad*4 + r;
          ostS[m*64 + t*4 + s] = v;
          ApS[(mt*9+8)*512 + (m&15)*8 + s] = f2bf(v);          // x_sp(t+1) feedback
        }
      }
    }
    __syncthreads();
  }
  // ---- decoder epilogue: head_cr(15) ----
  if (w >= 4){
    const int mt = w - 4;
    f32x4 hacc = (f32x4){0.f,0.f,0.f,0.f};
    #pragma unroll
    for (int kt = 0; kt < 9; ++kt){
      bf16x8 a  = *(const bf16x8*)&aP[(mt*9+kt)*512];
      bf16x8 bv = *(const bf16x8*)&headcr[((size_t)kt*64 + lane)*8];
      hacc = __builtin_amdgcn_mfma_f32_16x16x32_bf16(a, bv, hacc, 0, 0, 0);
    }
    const int s = col16;
    if (s >= 4 && s < 6){
      #pragma unroll
      for (int r = 0; r < 4; ++r){
        float v = fmaxf(hacc[r], 0.f);
        const float o = __shfl_xor(v, 1, 64);
        const int m = mt*16 + quad*4 + r;
        const float mx = fmaxf(v, o);
        const float e0 = __expf(v-mx), e1 = __expf(o-mx);
        ostC[m*32 + 15*2 + (s-4)] = e0*rcp_(e0+e1);
      }
    }
  }
  __syncthreads();

  // ---- coalesced output flush (non-temporal stores) ----
  for (int i = tid; i < 4096; i += 512){
    const int oi = (brow0 + (i>>6))*64 + (i&63);
    const float v = ostS[i];
    if (f32) __builtin_nontemporal_store(v, outf + oi);
    else     __builtin_nontemporal_store(f2bf(v), outu + oi);
  }
  for (int i = tid; i < 2048; i += 512){
    const int oi = 1048576 + (brow0 + (i>>5))*32 + (i&31);
    const float v = ostC[i];
    if (f32) __builtin_nontemporal_store(v, outf + oi);
    else     __builtin_nontemporal_store(f2bf(v), outu + oi);
  }
}

extern "C" void kernel_launch(void* const* d_in, const int* in_sizes, int n_in,
                              void* d_out, int out_size, void* d_ws, size_t ws_size,
                              hipStream_t stream) {
  PackArgs pa;
  pa.wih[0]=(const ushort_t*)d_in[2];  pa.whh[0]=(const ushort_t*)d_in[3];
  pa.bih[0]=(const ushort_t*)d_in[4];  pa.bhh[0]=(const ushort_t*)d_in[5];
  pa.wih[1]=(const ushort_t*)d_in[6];  pa.whh[1]=(const ushort_t*)d_in[7];
  pa.bih[1]=(const ushort_t*)d_in[8];  pa.bhh[1]=(const ushort_t*)d_in[9];
  pa.wih[2]=(const ushort_t*)d_in[10]; pa.whh[2]=(const ushort_t*)d_in[11];
  pa.bih[2]=(const ushort_t*)d_in[12]; pa.bhh[2]=(const ushort_t*)d_in[13];
  pa.wih[3]=(const ushort_t*)d_in[14]; pa.whh[3]=(const ushort_t*)d_in[15];
  pa.bih[3]=(const ushort_t*)d_in[16]; pa.bhh[3]=(const ushort_t*)d_in[17];
  pa.fcsp_w=(const ushort_t*)d_in[18]; pa.fcsp_b=(const ushort_t*)d_in[19];
  pa.fccr_w=(const ushort_t*)d_in[20]; pa.fccr_b=(const ushort_t*)d_in[21];
  pa.emb_w =(const ushort_t*)d_in[22]; pa.emb_b =(const ushort_t*)d_in[23];
  pa.ws = (ushort_t*)d_ws;

  hipLaunchKernelGGL(pack_kernel, dim3((PACK_TOTAL + 255)/256), dim3(256), 0, stream, pa);
  hipLaunchKernelGGL(pvlstm_main, dim3(256), dim3(512), 0, stream,
      (const ushort_t*)d_ws,
      (const ushort_t*)d_in[0], (const ushort_t*)d_in[1],
      d_out);
}

// Round 2
// 1129.047 us; speedup vs baseline: 2.6928x; 2.6928x over previous
//
#include <hip/hip_runtime.h>

typedef unsigned short ushort_t;
typedef __bf16 bf16x8 __attribute__((ext_vector_type(8)));
typedef float f32x4 __attribute__((ext_vector_type(4)));

#define PACK_W_ELEMS (8*9*8*512)           // 294912 bf16 per LSTM: [wave8][kt9][gu8][512]
#define HEAD_ELEMS   (9*512)               // 1 n-tile x 9 k-tiles
#define PACK_TOTAL   (4*PACK_W_ELEMS + 2*HEAD_ELEMS)
#define FLAG_OFS     PACK_TOTAL            // ushort index of int dtype flag

__device__ __forceinline__ float bf2f(ushort_t u){ return __uint_as_float(((unsigned)u)<<16); }
__device__ __forceinline__ ushort_t f2bf(float f){
  __bf16 h = (__bf16)f;                    // HW RTNE convert (values bounded)
  return *(ushort_t*)&h;
}
__device__ __forceinline__ float rcp_(float x){ return __builtin_amdgcn_rcpf(x); }
__device__ __forceinline__ float sigmf_(float x){ return rcp_(1.0f + __expf(-x)); }
__device__ __forceinline__ float tanhf_(float x){ return 1.0f - 2.0f*rcp_(1.0f + __expf(2.0f*x)); }

__device__ __forceinline__ int sniff_f32(const ushort_t* w){
  int f32 = 0;
  #pragma unroll
  for (int i = 0; i < 32; ++i){
    float f = bf2f(w[2*i]);
    if (!(f > -8.f && f < 8.f)) f32 = 1;
  }
  return f32;
}
__device__ __forceinline__ float ldin(const ushort_t* p, int i, int f32){
  return f32 ? ((const float*)p)[i] : bf2f(p[i]);
}
__device__ __forceinline__ float ldin_nt(const ushort_t* p, int i, int f32){
  return f32 ? __builtin_nontemporal_load((const float*)p + i)
             : bf2f(__builtin_nontemporal_load(p + i));
}
__device__ __forceinline__ ushort_t ldw(const ushort_t* p, int i, int f32){
  return f32 ? f2bf(((const float*)p)[i]) : p[i];
}

// ---------------- pack kernel (unchanged: B layout is row-count agnostic) ----------------
struct PackArgs {
  const ushort_t* wih[4]; const ushort_t* whh[4];
  const ushort_t* bih[4]; const ushort_t* bhh[4];
  const ushort_t* fcsp_w; const ushort_t* fcsp_b;
  const ushort_t* fccr_w; const ushort_t* fccr_b;
  const ushort_t* emb_w;  const ushort_t* emb_b;
  ushort_t* ws;
};

__global__ void pack_kernel(PackArgs a){
  const int f32 = sniff_f32(a.whh[0]);
  int idx = blockIdx.x*256 + threadIdx.x;
  if (blockIdx.x == 0 && threadIdx.x == 0) *(int*)(a.ws + FLAG_OFS) = f32;
  const int total_w = 4*PACK_W_ELEMS;
  if (idx < total_w){
    int l = idx / PACK_W_ELEMS;
    int r = idx % PACK_W_ELEMS;
    int j = r & 7;
    int lane = (r>>3) & 63;
    int tile = r >> 9;            // (wv*9 + kt)*8 + gu
    int gu = tile & 7;
    int kt = (tile >> 3) % 9;
    int wv = tile / 72;
    int g = gu >> 1, u = gu & 1;
    int n = (g*16 + wv*2 + u)*16 + (lane & 15);
    int k = kt*32 + ((lane>>4)<<3) + j;
    ushort_t v = 0;
    if (k < 256)       v = ldw(a.whh[l], n*256 + k, f32);
    else if (k < 260)  v = ldw(a.wih[l], n*4 + (k-256), f32);
    else if (k == 260) v = f2bf(ldin(a.bih[l], n, f32) + ldin(a.bhh[l], n, f32));
    a.ws[l*PACK_W_ELEMS + r] = v;
    return;
  }
  idx -= total_w;
  if (idx < 2*HEAD_ELEMS){
    int which = idx / HEAD_ELEMS;           // 0 = speed, 1 = cross
    int r = idx % HEAD_ELEMS;
    int j = r & 7; int lane = (r>>3)&63; int kt = r>>9;
    int n = lane & 15; int k = kt*32 + ((lane>>4)<<3) + j;
    ushort_t v = 0;
    if (which == 0){
      if (n < 4){
        if (k < 256)       v = ldw(a.fcsp_w, n*256 + k, f32);
        else if (k == 260) v = f2bf(ldin(a.fcsp_b, n, f32));
      }
    } else {
      if (n < 4){
        if (k < 256)       v = ldw(a.emb_w, n*256 + k, f32);
        else if (k == 260) v = f2bf(ldin(a.emb_b, n, f32));
      } else if (n < 6){
        if (k < 256)       v = ldw(a.fccr_w, (n-4)*256 + k, f32);
        else if (k == 260) v = f2bf(ldin(a.fccr_b, n-4, f32));
      }
    }
    a.ws[total_w + idx] = v;
  }
}

// ---------------- serial gate GEMM (proven r0 structure, mt=2) ----------------
// Software-pipelined: B loads run one half-kt group ahead of their MFMAs.
// acc 64 f32 (AGPR); per-element accumulation order identical to the 848us baseline.
__device__ __forceinline__ void gate_gemm(const ushort_t* __restrict__ Aln,   // ApX + lane*8
                                          const ushort_t* __restrict__ bw,   // wave pack + lane*8
                                          f32x4 (&acc)[2][8]){
  #pragma unroll
  for (int i = 0; i < 2; ++i)
    #pragma unroll
    for (int j = 0; j < 8; ++j) acc[i][j] = (f32x4){0.f,0.f,0.f,0.f};
  // preload half0 of kt0 (gu 0..3)
  bf16x8 p0 = *(const bf16x8*)&bw[0*512];
  bf16x8 p1 = *(const bf16x8*)&bw[1*512];
  bf16x8 p2 = *(const bf16x8*)&bw[2*512];
  bf16x8 p3 = *(const bf16x8*)&bw[3*512];
  const ushort_t* bp = bw;
  #pragma unroll 1
  for (int kt = 0; kt < 9; ++kt){
    // load half1 of this kt (gu 4..7)
    bf16x8 q0 = *(const bf16x8*)&bp[4*512];
    bf16x8 q1 = *(const bf16x8*)&bp[5*512];
    bf16x8 q2 = *(const bf16x8*)&bp[6*512];
    bf16x8 q3 = *(const bf16x8*)&bp[7*512];
    bf16x8 a0 = *(const bf16x8*)&Aln[(0*9+kt)*512];
    bf16x8 a1 = *(const bf16x8*)&Aln[(1*9+kt)*512];
    acc[0][0] = __builtin_amdgcn_mfma_f32_16x16x32_bf16(a0, p0, acc[0][0], 0, 0, 0);
    acc[1][0] = __builtin_amdgcn_mfma_f32_16x16x32_bf16(a1, p0, acc[1][0], 0, 0, 0);
    acc[0][1] = __builtin_amdgcn_mfma_f32_16x16x32_bf16(a0, p1, acc[0][1], 0, 0, 0);
    acc[1][1] = __builtin_amdgcn_mfma_f32_16x16x32_bf16(a1, p1, acc[1][1], 0, 0, 0);
    acc[0][2] = __builtin_amdgcn_mfma_f32_16x16x32_bf16(a0, p2, acc[0][2], 0, 0, 0);
    acc[1][2] = __builtin_amdgcn_mfma_f32_16x16x32_bf16(a1, p2, acc[1][2], 0, 0, 0);
    acc[0][3] = __builtin_amdgcn_mfma_f32_16x16x32_bf16(a0, p3, acc[0][3], 0, 0, 0);
    acc[1][3] = __builtin_amdgcn_mfma_f32_16x16x32_bf16(a1, p3, acc[1][3], 0, 0, 0);
    // prefetch half0 of next kt (hidden under half1's MFMAs)
    if (kt < 8){
      p0 = *(const bf16x8*)&bp[4096 + 0*512];
      p1 = *(const bf16x8*)&bp[4096 + 1*512];
      p2 = *(const bf16x8*)&bp[4096 + 2*512];
      p3 = *(const bf16x8*)&bp[4096 + 3*512];
    }
    acc[0][4] = __builtin_amdgcn_mfma_f32_16x16x32_bf16(a0, q0, acc[0][4], 0, 0, 0);
    acc[1][4] = __builtin_amdgcn_mfma_f32_16x16x32_bf16(a1, q0, acc[1][4], 0, 0, 0);
    acc[0][5] = __builtin_amdgcn_mfma_f32_16x16x32_bf16(a0, q1, acc[0][5], 0, 0, 0);
    acc[1][5] = __builtin_amdgcn_mfma_f32_16x16x32_bf16(a1, q1, acc[1][5], 0, 0, 0);
    acc[0][6] = __builtin_amdgcn_mfma_f32_16x16x32_bf16(a0, q2, acc[0][6], 0, 0, 0);
    acc[1][6] = __builtin_amdgcn_mfma_f32_16x16x32_bf16(a1, q2, acc[1][6], 0, 0, 0);
    acc[0][7] = __builtin_amdgcn_mfma_f32_16x16x32_bf16(a0, q3, acc[0][7], 0, 0, 0);
    acc[1][7] = __builtin_amdgcn_mfma_f32_16x16x32_bf16(a1, q3, acc[1][7], 0, 0, 0);
    bp += 4096;
  }
}

// gate nonlinearity + h writeback; acc idx: i->u, f->2+u, g->4+u, o->6+u
__device__ __forceinline__ void gates_wb(f32x4 (&acc)[2][8], float (&cw)[2][2][4],
                                         ushort_t* __restrict__ Ap, int wbBase){
  #pragma unroll
  for (int mt = 0; mt < 2; ++mt)
    #pragma unroll
    for (int u = 0; u < 2; ++u)
      #pragma unroll
      for (int r = 0; r < 4; ++r){
        float cn = sigmf_(acc[mt][2+u][r])*cw[mt][u][r]
                 + sigmf_(acc[mt][u][r])*tanhf_(acc[mt][4+u][r]);
        float hn = sigmf_(acc[mt][6+u][r])*tanhf_(cn);
        cw[mt][u][r] = cn;
        Ap[mt*4608 + u*256 + r*8 + wbBase] = f2bf(hn);
      }
}

// ---------------- main kernel: 512 blocks x 32 rows, 512 threads (8 waves) ----------------
// 2 blocks/CU (56 KB LDS, 192 regs/wave): co-resident blocks drift anti-phase so one
// block's gate-VALU overlaps the other's GEMM MFMAs (TLP overlap, no fusion).
__global__ __launch_bounds__(512, 4) void pvlstm_main(
    const ushort_t* __restrict__ ws,
    const ushort_t* __restrict__ speed,
    const ushort_t* __restrict__ pos,
    void* __restrict__ outv)
{
  __shared__ ushort_t ApS[2*9*512];   // A-pack speed-enc / speed-dec (18 KB)
  __shared__ ushort_t ApP[2*9*512];   // A-pack pos-enc / cross-dec   (18 KB)
  __shared__ ushort_t xsS[32*64];     // staged speed inputs (4 KB)
  __shared__ ushort_t xsP[32*64];     // staged pos inputs   (4 KB)
  __shared__ float    ostS[32*64];    // speed outputs stage (8 KB)
  __shared__ float    ostC[32*32];    // crossing outputs stage (4 KB)

  const int f32   = *(const int*)(ws + FLAG_OFS);
  const int tid   = threadIdx.x;
  const int lane  = tid & 63;
  const int w     = tid >> 6;   // 0..7
  const int col16 = lane & 15;
  const int quad  = lane >> 4;
  const int brow0 = blockIdx.x * 32;
  const int wbBase = w*512 + (col16>>3)*128 + quad*32 + (col16&7);

  ushort_t* outu = (ushort_t*)outv;
  float*    outf = (float*)outv;

  const ushort_t* headsp = ws + 4*PACK_W_ELEMS;
  const ushort_t* headcr = headsp + HEAD_ELEMS;
  const ushort_t* aS  = ApS + lane*8;
  const ushort_t* aP  = ApP + lane*8;
  const ushort_t* bwS  = ws + 0*PACK_W_ELEMS + (size_t)w*36864 + (size_t)lane*8;
  const ushort_t* bwP  = ws + 1*PACK_W_ELEMS + (size_t)w*36864 + (size_t)lane*8;
  const ushort_t* bwDS = ws + 2*PACK_W_ELEMS + (size_t)w*36864 + (size_t)lane*8;
  const ushort_t* bwDC = ws + 3*PACK_W_ELEMS + (size_t)w*36864 + (size_t)lane*8;

  float cwA[2][2][4], cwB[2][2][4];
  f32x4 acc[2][8];

  // ---- prologue: stage inputs (non-temporal), zero A-packs, bias column, x_sp(0) ----
  for (int i = tid; i < 2048; i += 512){
    int gi = (brow0 + (i>>6))*64 + (i&63);
    xsS[i] = f2bf(ldin_nt(speed, gi, f32));
    xsP[i] = f2bf(ldin_nt(pos,   gi, f32));
  }
  for (int i = tid; i < 2*9*512/2; i += 512){
    ((unsigned*)ApS)[i] = 0u; ((unsigned*)ApP)[i] = 0u;
  }
  #pragma unroll
  for (int mt = 0; mt < 2; ++mt)
    #pragma unroll
    for (int u = 0; u < 2; ++u)
      #pragma unroll
      for (int r = 0; r < 4; ++r){ cwA[mt][u][r] = 0.f; cwB[mt][u][r] = 0.f; }
  __syncthreads();
  if (tid < 32){
    ushort_t* xpS = &ApS[((tid>>4)*9 + 8)*512 + (tid&15)*8];
    ushort_t* xpP = &ApP[((tid>>4)*9 + 8)*512 + (tid&15)*8];
    *(uint2*)xpS = *(const uint2*)&xsS[tid*64];    // x_sp(0)
    xpS[4] = (ushort_t)0x3f80;                     // bias 1.0 column
    xpP[4] = (ushort_t)0x3f80;
  }
  __syncthreads();

  // ================= encoders: sp (A) and po (B), interleaved =================
  for (int t = 0; t < 16; ++t){
    // R1: gates_po(t-1)+wb -> ApP ; x_po(t) -> ApP.kt8 ; GEMM_sp(t) from ApS
    if (t > 0) gates_wb(acc, cwB, ApP, wbBase);
    if (tid < 32)
      *(uint2*)&ApP[((tid>>4)*9 + 8)*512 + (tid&15)*8] = *(const uint2*)&xsP[tid*64 + t*4];
    gate_gemm(aS, bwS, acc);
    __syncthreads();
    // R2: gates_sp(t)+wb -> ApS ; x_sp(t+1) -> ApS.kt8 ; GEMM_po(t) from ApP
    gates_wb(acc, cwA, ApS, wbBase);
    if (t < 15 && tid < 32)
      *(uint2*)&ApS[((tid>>4)*9 + 8)*512 + (tid&15)*8] = *(const uint2*)&xsS[tid*64 + t*4 + 4];
    gate_gemm(aP, bwP, acc);
    __syncthreads();
  }
  // ---- encoder epilogue: gates_po(15); h0 = h_sp+h_po into BOTH packs; c0 in regs ----
  #pragma unroll
  for (int mt = 0; mt < 2; ++mt)
    #pragma unroll
    for (int u = 0; u < 2; ++u)
      #pragma unroll
      for (int r = 0; r < 4; ++r){
        float cn = sigmf_(acc[mt][2+u][r])*cwB[mt][u][r]
                 + sigmf_(acc[mt][u][r])*tanhf_(acc[mt][4+u][r]);
        float hn = sigmf_(acc[mt][6+u][r])*tanhf_(cn);
        float c0 = cwA[mt][u][r] + cn;
        cwA[mt][u][r] = c0; cwB[mt][u][r] = c0;
        const int ad = mt*4608 + u*256 + r*8 + wbBase;
        ushort_t h0 = f2bf(bf2f(ApS[ad]) + hn);    // h_sp(15) written in R2(15)
        ApS[ad] = h0; ApP[ad] = h0;
      }
  if (tid < 32){
    *(uint2*)&ApS[((tid>>4)*9 + 8)*512 + (tid&15)*8] = *(const uint2*)&xsS[tid*64 + 60];  // x0 sp
    *(uint2*)&ApP[((tid>>4)*9 + 8)*512 + (tid&15)*8] = *(const uint2*)&xsP[tid*64 + 60];  // x0 po
  }
  __syncthreads();

  // ================= decoders: dsp (A, ApS) and dcr (B, ApP), interleaved =================
  for (int t = 0; t < 16; ++t){
    // R1: head_cr(t-1) [waves 4..5] -> ostC + x_cr(t) ; GEMM_dsp(t) from ApS
    if (t > 0 && w >= 4 && w < 6){
      const int mt = w - 4;
      f32x4 hacc = (f32x4){0.f,0.f,0.f,0.f};
      #pragma unroll
      for (int kt = 0; kt < 9; ++kt){
        bf16x8 a  = *(const bf16x8*)&aP[(mt*9+kt)*512];
        bf16x8 bv = *(const bf16x8*)&headcr[((size_t)kt*64 + lane)*8];
        hacc = __builtin_amdgcn_mfma_f32_16x16x32_bf16(a, bv, hacc, 0, 0, 0);
      }
      const int s = col16;
      #pragma unroll
      for (int r = 0; r < 4; ++r){
        float v = fmaxf(hacc[r], 0.f);             // relu
        const float o = __shfl_xor(v, 1, 64);      // pair logits (lanes 4<->5)
        const int m = mt*16 + quad*4 + r;
        if (s < 4){
          ApP[(mt*9+8)*512 + (m&15)*8 + s] = f2bf(v);          // x_cr(t) feedback
        } else if (s < 6){
          const float mx = fmaxf(v, o);
          const float e0 = __expf(v-mx), e1 = __expf(o-mx);
          ostC[m*32 + (t-1)*2 + (s-4)] = e0*rcp_(e0+e1);       // softmax2 at t-1
        }
      }
    }
    gate_gemm(aS, bwDS, acc);
    __syncthreads();
    // R2: gates_dsp(t)+wb -> ApS ; GEMM_dcr(t) from ApP
    gates_wb(acc, cwA, ApS, wbBase);
    gate_gemm(aP, bwDC, acc);
    __syncthreads();
    // R3: gates_dcr(t)+wb -> ApP ; head_sp(t) [waves 0..1] -> ostS + x_sp(t+1)
    gates_wb(acc, cwB, ApP, wbBase);
    if (w < 2){
      const int mt = w;
      f32x4 hacc = (f32x4){0.f,0.f,0.f,0.f};
      #pragma unroll
      for (int kt = 0; kt < 9; ++kt){
        bf16x8 a  = *(const bf16x8*)&aS[(mt*9+kt)*512];
        bf16x8 bv = *(const bf16x8*)&headsp[((size_t)kt*64 + lane)*8];
        hacc = __builtin_amdgcn_mfma_f32_16x16x32_bf16(a, bv, hacc, 0, 0, 0);
      }
      const int s = col16;
      if (s < 4){
        #pragma unroll
        for (int r = 0; r < 4; ++r){
          float v = fminf(fmaxf(hacc[r], -100.f), 100.f);      // hardtanh(+-100)
          const int m = mt*16 + quad*4 + r;
          ostS[m*64 + t*4 + s] = v;
          ApS[(mt*9+8)*512 + (m&15)*8 + s] = f2bf(v);          // x_sp(t+1) feedback
        }
      }
    }
    __syncthreads();
  }
  // ---- decoder epilogue: head_cr(15) ----
  if (w >= 4 && w < 6){
    const int mt = w - 4;
    f32x4 hacc = (f32x4){0.f,0.f,0.f,0.f};
    #pragma unroll
    for (int kt = 0; kt < 9; ++kt){
      bf16x8 a  = *(const bf16x8*)&aP[(mt*9+kt)*512];
      bf16x8 bv = *(const bf16x8*)&headcr[((size_t)kt*64 + lane)*8];
      hacc = __builtin_amdgcn_mfma_f32_16x16x32_bf16(a, bv, hacc, 0, 0, 0);
    }
    const int s = col16;
    if (s >= 4 && s < 6){
      #pragma unroll
      for (int r = 0; r < 4; ++r){
        float v = fmaxf(hacc[r], 0.f);
        const float o = __shfl_xor(v, 1, 64);
        const int m = mt*16 + quad*4 + r;
        const float mx = fmaxf(v, o);
        const float e0 = __expf(v-mx), e1 = __expf(o-mx);
        ostC[m*32 + 15*2 + (s-4)] = e0*rcp_(e0+e1);
      }
    }
  }
  __syncthreads();

  // ---- coalesced output flush (non-temporal stores) ----
  for (int i = tid; i < 2048; i += 512){
    const int oi = (brow0 + (i>>6))*64 + (i&63);
    const float v = ostS[i];
    if (f32) __builtin_nontemporal_store(v, outf + oi);
    else     __builtin_nontemporal_store(f2bf(v), outu + oi);
  }
  for (int i = tid; i < 1024; i += 512){
    const int oi = 1048576 + (brow0 + (i>>5))*32 + (i&31);
    const float v = ostC[i];
    if (f32) __builtin_nontemporal_store(v, outf + oi);
    else     __builtin_nontemporal_store(f2bf(v), outu + oi);
  }
}

extern "C" void kernel_launch(void* const* d_in, const int* in_sizes, int n_in,
                              void* d_out, int out_size, void* d_ws, size_t ws_size,
                              hipStream_t stream) {
  PackArgs pa;
  pa.wih[0]=(const ushort_t*)d_in[2];  pa.whh[0]=(const ushort_t*)d_in[3];
  pa.bih[0]=(const ushort_t*)d_in[4];  pa.bhh[0]=(const ushort_t*)d_in[5];
  pa.wih[1]=(const ushort_t*)d_in[6];  pa.whh[1]=(const ushort_t*)d_in[7];
  pa.bih[1]=(const ushort_t*)d_in[8];  pa.bhh[1]=(const ushort_t*)d_in[9];
  pa.wih[2]=(const ushort_t*)d_in[10]; pa.whh[2]=(const ushort_t*)d_in[11];
  pa.bih[2]=(const ushort_t*)d_in[12]; pa.bhh[2]=(const ushort_t*)d_in[13];
  pa.wih[3]=(const ushort_t*)d_in[14]; pa.whh[3]=(const ushort_t*)d_in[15];
  pa.bih[3]=(const ushort_t*)d_in[16]; pa.bhh[3]=(const ushort_t*)d_in[17];
  pa.fcsp_w=(const ushort_t*)d_in[18]; pa.fcsp_b=(const ushort_t*)d_in[19];
  pa.fccr_w=(const ushort_t*)d_in[20]; pa.fccr_b=(const ushort_t*)d_in[21];
  pa.emb_w =(const ushort_t*)d_in[22]; pa.emb_b =(const ushort_t*)d_in[23];
  pa.ws = (ushort_t*)d_ws;

  hipLaunchKernelGGL(pack_kernel, dim3((PACK_TOTAL + 255)/256), dim3(256), 0, stream, pa);
  hipLaunchKernelGGL(pvlstm_main, dim3(512), dim3(512), 0, stream,
      (const ushort_t*)d_ws,
      (const ushort_t*)d_in[0], (const ushort_t*)d_in[1],
      d_out);
}

// Round 5
// 930.482 us; speedup vs baseline: 3.2675x; 1.2134x over previous
//
#include <hip/hip_runtime.h>

typedef unsigned short ushort_t;
typedef __bf16 bf16x8 __attribute__((ext_vector_type(8)));
typedef float f32x4 __attribute__((ext_vector_type(4)));

#define PACK_W_ELEMS (8*9*8*512)           // 294912 bf16 per LSTM: [wave8][kt9][gu8][512]
#define HEAD_ELEMS   (9*512)               // 1 n-tile x 9 k-tiles
#define PACK_TOTAL   (4*PACK_W_ELEMS + 2*HEAD_ELEMS)
#define FLAG_OFS     PACK_TOTAL            // ushort index of int dtype flag

__device__ __forceinline__ float bf2f(ushort_t u){ return __uint_as_float(((unsigned)u)<<16); }
__device__ __forceinline__ ushort_t f2bf(float f){
  __bf16 h = (__bf16)f;                    // HW RTNE convert (values bounded)
  return *(ushort_t*)&h;
}
__device__ __forceinline__ float rcp_(float x){ return __builtin_amdgcn_rcpf(x); }
__device__ __forceinline__ float sigmf_(float x){ return rcp_(1.0f + __expf(-x)); }
__device__ __forceinline__ float tanhf_(float x){ return 1.0f - 2.0f*rcp_(1.0f + __expf(2.0f*x)); }

__device__ __forceinline__ int sniff_f32(const ushort_t* w){
  int f32 = 0;
  #pragma unroll
  for (int i = 0; i < 32; ++i){
    float f = bf2f(w[2*i]);
    if (!(f > -8.f && f < 8.f)) f32 = 1;
  }
  return f32;
}
__device__ __forceinline__ float ldin(const ushort_t* p, int i, int f32){
  return f32 ? ((const float*)p)[i] : bf2f(p[i]);
}
__device__ __forceinline__ float ldin_nt(const ushort_t* p, int i, int f32){
  return f32 ? __builtin_nontemporal_load((const float*)p + i)
             : bf2f(__builtin_nontemporal_load(p + i));
}
__device__ __forceinline__ ushort_t ldw(const ushort_t* p, int i, int f32){
  return f32 ? f2bf(((const float*)p)[i]) : p[i];
}

// ---------------- pack kernel (unchanged: B layout is row-count agnostic) ----------------
struct PackArgs {
  const ushort_t* wih[4]; const ushort_t* whh[4];
  const ushort_t* bih[4]; const ushort_t* bhh[4];
  const ushort_t* fcsp_w; const ushort_t* fcsp_b;
  const ushort_t* fccr_w; const ushort_t* fccr_b;
  const ushort_t* emb_w;  const ushort_t* emb_b;
  ushort_t* ws;
};

__global__ void pack_kernel(PackArgs a){
  const int f32 = sniff_f32(a.whh[0]);
  int idx = blockIdx.x*256 + threadIdx.x;
  if (blockIdx.x == 0 && threadIdx.x == 0) *(int*)(a.ws + FLAG_OFS) = f32;
  const int total_w = 4*PACK_W_ELEMS;
  if (idx < total_w){
    int l = idx / PACK_W_ELEMS;
    int r = idx % PACK_W_ELEMS;
    int j = r & 7;
    int lane = (r>>3) & 63;
    int tile = r >> 9;            // (wv*9 + kt)*8 + gu
    int gu = tile & 7;
    int kt = (tile >> 3) % 9;
    int wv = tile / 72;
    int g = gu >> 1, u = gu & 1;
    int n = (g*16 + wv*2 + u)*16 + (lane & 15);
    int k = kt*32 + ((lane>>4)<<3) + j;
    ushort_t v = 0;
    if (k < 256)       v = ldw(a.whh[l], n*256 + k, f32);
    else if (k < 260)  v = ldw(a.wih[l], n*4 + (k-256), f32);
    else if (k == 260) v = f2bf(ldin(a.bih[l], n, f32) + ldin(a.bhh[l], n, f32));
    a.ws[l*PACK_W_ELEMS + r] = v;
    return;
  }
  idx -= total_w;
  if (idx < 2*HEAD_ELEMS){
    int which = idx / HEAD_ELEMS;           // 0 = speed, 1 = cross
    int r = idx % HEAD_ELEMS;
    int j = r & 7; int lane = (r>>3)&63; int kt = r>>9;
    int n = lane & 15; int k = kt*32 + ((lane>>4)<<3) + j;
    ushort_t v = 0;
    if (which == 0){
      if (n < 4){
        if (k < 256)       v = ldw(a.fcsp_w, n*256 + k, f32);
        else if (k == 260) v = f2bf(ldin(a.fcsp_b, n, f32));
      }
    } else {
      if (n < 4){
        if (k < 256)       v = ldw(a.emb_w, n*256 + k, f32);
        else if (k == 260) v = f2bf(ldin(a.emb_b, n, f32));
      } else if (n < 6){
        if (k < 256)       v = ldw(a.fccr_w, (n-4)*256 + k, f32);
        else if (k == 260) v = f2bf(ldin(a.fccr_b, n-4, f32));
      }
    }
    a.ws[total_w + idx] = v;
  }
}

// ---------------- serial gate GEMM, mt=2, SINGLE-buffered B ----------------
// Register-lean variant: only one 4-tile B group live at a time (16 VGPR), so
// arch regs fit the 64-slot budget at 4 waves/SIMD (acc 64 AGPR + arch 64 = 128).
// Exposed per-group L2 latency is covered by cross-phase TLP (2 blocks/CU).
// MFMA order (kt ascending, gu 0..3 then 4..7) identical to baseline -> bit-identical.
__device__ __forceinline__ void gate_gemm(const ushort_t* __restrict__ Aln,   // ApX + lane*8
                                          const ushort_t* __restrict__ bw,   // pack + wave/lane off
                                          f32x4 (&acc)[2][8]){
  #pragma unroll
  for (int i = 0; i < 2; ++i)
    #pragma unroll
    for (int j = 0; j < 8; ++j) acc[i][j] = (f32x4){0.f,0.f,0.f,0.f};
  #pragma unroll 1
  for (int kt = 0; kt < 9; ++kt){
    const ushort_t* bp = bw + kt*4096;
    bf16x8 a0 = *(const bf16x8*)&Aln[(0*9+kt)*512];
    bf16x8 a1 = *(const bf16x8*)&Aln[(1*9+kt)*512];
    {
      bf16x8 b0 = *(const bf16x8*)&bp[0*512];
      bf16x8 b1 = *(const bf16x8*)&bp[1*512];
      bf16x8 b2 = *(const bf16x8*)&bp[2*512];
      bf16x8 b3 = *(const bf16x8*)&bp[3*512];
      acc[0][0] = __builtin_amdgcn_mfma_f32_16x16x32_bf16(a0, b0, acc[0][0], 0, 0, 0);
      acc[1][0] = __builtin_amdgcn_mfma_f32_16x16x32_bf16(a1, b0, acc[1][0], 0, 0, 0);
      acc[0][1] = __builtin_amdgcn_mfma_f32_16x16x32_bf16(a0, b1, acc[0][1], 0, 0, 0);
      acc[1][1] = __builtin_amdgcn_mfma_f32_16x16x32_bf16(a1, b1, acc[1][1], 0, 0, 0);
      acc[0][2] = __builtin_amdgcn_mfma_f32_16x16x32_bf16(a0, b2, acc[0][2], 0, 0, 0);
      acc[1][2] = __builtin_amdgcn_mfma_f32_16x16x32_bf16(a1, b2, acc[1][2], 0, 0, 0);
      acc[0][3] = __builtin_amdgcn_mfma_f32_16x16x32_bf16(a0, b3, acc[0][3], 0, 0, 0);
      acc[1][3] = __builtin_amdgcn_mfma_f32_16x16x32_bf16(a1, b3, acc[1][3], 0, 0, 0);
    }
    {
      bf16x8 b4 = *(const bf16x8*)&bp[4*512];
      bf16x8 b5 = *(const bf16x8*)&bp[5*512];
      bf16x8 b6 = *(const bf16x8*)&bp[6*512];
      bf16x8 b7 = *(const bf16x8*)&bp[7*512];
      acc[0][4] = __builtin_amdgcn_mfma_f32_16x16x32_bf16(a0, b4, acc[0][4], 0, 0, 0);
      acc[1][4] = __builtin_amdgcn_mfma_f32_16x16x32_bf16(a1, b4, acc[1][4], 0, 0, 0);
      acc[0][5] = __builtin_amdgcn_mfma_f32_16x16x32_bf16(a0, b5, acc[0][5], 0, 0, 0);
      acc[1][5] = __builtin_amdgcn_mfma_f32_16x16x32_bf16(a1, b5, acc[1][5], 0, 0, 0);
      acc[0][6] = __builtin_amdgcn_mfma_f32_16x16x32_bf16(a0, b6, acc[0][6], 0, 0, 0);
      acc[1][6] = __builtin_amdgcn_mfma_f32_16x16x32_bf16(a1, b6, acc[1][6], 0, 0, 0);
      acc[0][7] = __builtin_amdgcn_mfma_f32_16x16x32_bf16(a0, b7, acc[0][7], 0, 0, 0);
      acc[1][7] = __builtin_amdgcn_mfma_f32_16x16x32_bf16(a1, b7, acc[1][7], 0, 0, 0);
    }
  }
}

// gate nonlinearity + h writeback; acc idx: i->u, f->2+u, g->4+u, o->6+u
__device__ __forceinline__ void gates_wb(f32x4 (&acc)[2][8], float (&cw)[2][2][4],
                                         ushort_t* __restrict__ Ap, int wbBase){
  #pragma unroll
  for (int mt = 0; mt < 2; ++mt)
    #pragma unroll
    for (int u = 0; u < 2; ++u)
      #pragma unroll
      for (int r = 0; r < 4; ++r){
        float cn = sigmf_(acc[mt][2+u][r])*cw[mt][u][r]
                 + sigmf_(acc[mt][u][r])*tanhf_(acc[mt][4+u][r]);
        float hn = sigmf_(acc[mt][6+u][r])*tanhf_(cn);
        cw[mt][u][r] = cn;
        Ap[mt*4608 + u*256 + r*8 + wbBase] = f2bf(hn);
      }
}

// ---------------- main kernel: 512 blocks x 32 rows, 512 threads (8 waves) ----------------
// 2 blocks/CU (56 KB LDS, 128 unified regs/wave): co-resident blocks drift anti-phase
// so one block's gate-VALU overlaps the other's GEMM MFMAs.
__global__ __launch_bounds__(512, 4) void pvlstm_main(
    const ushort_t* __restrict__ ws,
    const ushort_t* __restrict__ speed,
    const ushort_t* __restrict__ pos,
    void* __restrict__ outv)
{
  __shared__ ushort_t ApS[2*9*512];   // A-pack speed-enc / speed-dec (18 KB)
  __shared__ ushort_t ApP[2*9*512];   // A-pack pos-enc / cross-dec   (18 KB)
  __shared__ ushort_t xsS[32*64];     // staged speed inputs (4 KB)
  __shared__ ushort_t xsP[32*64];     // staged pos inputs   (4 KB)
  __shared__ float    ostS[32*64];    // speed outputs stage (8 KB)
  __shared__ float    ostC[32*32];    // crossing outputs stage (4 KB)

  const int f32   = *(const int*)(ws + FLAG_OFS);
  const int tid   = threadIdx.x;
  const int lane  = tid & 63;
  const int w     = tid >> 6;   // 0..7
  const int col16 = lane & 15;
  const int quad  = lane >> 4;
  const int brow0 = blockIdx.x * 32;
  const int wbBase = w*512 + (col16>>3)*128 + quad*32 + (col16&7);

  ushort_t* outu = (ushort_t*)outv;
  float*    outf = (float*)outv;

  const ushort_t* headsp = ws + 4*PACK_W_ELEMS;
  const ushort_t* headcr = headsp + HEAD_ELEMS;
  const ushort_t* aS  = ApS + lane*8;
  const ushort_t* aP  = ApP + lane*8;
  // Single per-lane B offset; pack selection is a constant add at each call site.
  const ushort_t* bwB = ws + (unsigned)(w*36864 + lane*8);

  float cwA[2][2][4], cwB[2][2][4];
  f32x4 acc[2][8];

  // ---- prologue: stage inputs (non-temporal), zero A-packs, bias column, x_sp(0) ----
  for (int i = tid; i < 2048; i += 512){
    int gi = (brow0 + (i>>6))*64 + (i&63);
    xsS[i] = f2bf(ldin_nt(speed, gi, f32));
    xsP[i] = f2bf(ldin_nt(pos,   gi, f32));
  }
  for (int i = tid; i < 2*9*512/2; i += 512){
    ((unsigned*)ApS)[i] = 0u; ((unsigned*)ApP)[i] = 0u;
  }
  #pragma unroll
  for (int mt = 0; mt < 2; ++mt)
    #pragma unroll
    for (int u = 0; u < 2; ++u)
      #pragma unroll
      for (int r = 0; r < 4; ++r){ cwA[mt][u][r] = 0.f; cwB[mt][u][r] = 0.f; }
  __syncthreads();
  if (tid < 32){
    ushort_t* xpS = &ApS[((tid>>4)*9 + 8)*512 + (tid&15)*8];
    ushort_t* xpP = &ApP[((tid>>4)*9 + 8)*512 + (tid&15)*8];
    *(uint2*)xpS = *(const uint2*)&xsS[tid*64];    // x_sp(0)
    xpS[4] = (ushort_t)0x3f80;                     // bias 1.0 column
    xpP[4] = (ushort_t)0x3f80;
  }
  __syncthreads();

  // ================= encoders: sp (A) and po (B), interleaved =================
  for (int t = 0; t < 16; ++t){
    // R1: gates_po(t-1)+wb -> ApP ; x_po(t) -> ApP.kt8 ; GEMM_sp(t) from ApS
    if (t > 0) gates_wb(acc, cwB, ApP, wbBase);
    if (tid < 32)
      *(uint2*)&ApP[((tid>>4)*9 + 8)*512 + (tid&15)*8] = *(const uint2*)&xsP[tid*64 + t*4];
    gate_gemm(aS, bwB + 0*PACK_W_ELEMS, acc);
    __syncthreads();
    // R2: gates_sp(t)+wb -> ApS ; x_sp(t+1) -> ApS.kt8 ; GEMM_po(t) from ApP
    gates_wb(acc, cwA, ApS, wbBase);
    if (t < 15 && tid < 32)
      *(uint2*)&ApS[((tid>>4)*9 + 8)*512 + (tid&15)*8] = *(const uint2*)&xsS[tid*64 + t*4 + 4];
    gate_gemm(aP, bwB + 1*PACK_W_ELEMS, acc);
    __syncthreads();
  }
  // ---- encoder epilogue: gates_po(15); h0 = h_sp+h_po into BOTH packs; c0 in regs ----
  #pragma unroll
  for (int mt = 0; mt < 2; ++mt)
    #pragma unroll
    for (int u = 0; u < 2; ++u)
      #pragma unroll
      for (int r = 0; r < 4; ++r){
        float cn = sigmf_(acc[mt][2+u][r])*cwB[mt][u][r]
                 + sigmf_(acc[mt][u][r])*tanhf_(acc[mt][4+u][r]);
        float hn = sigmf_(acc[mt][6+u][r])*tanhf_(cn);
        float c0 = cwA[mt][u][r] + cn;
        cwA[mt][u][r] = c0; cwB[mt][u][r] = c0;
        const int ad = mt*4608 + u*256 + r*8 + wbBase;
        ushort_t h0 = f2bf(bf2f(ApS[ad]) + hn);    // h_sp(15) written in R2(15)
        ApS[ad] = h0; ApP[ad] = h0;
      }
  if (tid < 32){
    *(uint2*)&ApS[((tid>>4)*9 + 8)*512 + (tid&15)*8] = *(const uint2*)&xsS[tid*64 + 60];  // x0 sp
    *(uint2*)&ApP[((tid>>4)*9 + 8)*512 + (tid&15)*8] = *(const uint2*)&xsP[tid*64 + 60];  // x0 po
  }
  __syncthreads();

  // ================= decoders: dsp (A, ApS) and dcr (B, ApP), interleaved =================
  for (int t = 0; t < 16; ++t){
    // R1: head_cr(t-1) [waves 4..5] -> ostC + x_cr(t) ; GEMM_dsp(t) from ApS
    if (t > 0 && w >= 4 && w < 6){
      const int mt = w - 4;
      f32x4 hacc = (f32x4){0.f,0.f,0.f,0.f};
      #pragma unroll
      for (int kt = 0; kt < 9; ++kt){
        bf16x8 a  = *(const bf16x8*)&aP[(mt*9+kt)*512];
        bf16x8 bv = *(const bf16x8*)&headcr[((size_t)kt*64 + lane)*8];
        hacc = __builtin_amdgcn_mfma_f32_16x16x32_bf16(a, bv, hacc, 0, 0, 0);
      }
      const int s = col16;
      #pragma unroll
      for (int r = 0; r < 4; ++r){
        float v = fmaxf(hacc[r], 0.f);             // relu
        const float o = __shfl_xor(v, 1, 64);      // pair logits (lanes 4<->5)
        const int m = mt*16 + quad*4 + r;
        if (s < 4){
          ApP[(mt*9+8)*512 + (m&15)*8 + s] = f2bf(v);          // x_cr(t) feedback
        } else if (s < 6){
          const float mx = fmaxf(v, o);
          const float e0 = __expf(v-mx), e1 = __expf(o-mx);
          ostC[m*32 + (t-1)*2 + (s-4)] = e0*rcp_(e0+e1);       // softmax2 at t-1
        }
      }
    }
    gate_gemm(aS, bwB + 2*PACK_W_ELEMS, acc);
    __syncthreads();
    // R2: gates_dsp(t)+wb -> ApS ; GEMM_dcr(t) from ApP
    gates_wb(acc, cwA, ApS, wbBase);
    gate_gemm(aP, bwB + 3*PACK_W_ELEMS, acc);
    __syncthreads();
    // R3: gates_dcr(t)+wb -> ApP ; head_sp(t) [waves 0..1] -> ostS + x_sp(t+1)
    gates_wb(acc, cwB, ApP, wbBase);
    if (w < 2){
      const int mt = w;
      f32x4 hacc = (f32x4){0.f,0.f,0.f,0.f};
      #pragma unroll
      for (int kt = 0; kt < 9; ++kt){
        bf16x8 a  = *(const bf16x8*)&aS[(mt*9+kt)*512];
        bf16x8 bv = *(const bf16x8*)&headsp[((size_t)kt*64 + lane)*8];
        hacc = __builtin_amdgcn_mfma_f32_16x16x32_bf16(a, bv, hacc, 0, 0, 0);
      }
      const int s = col16;
      if (s < 4){
        #pragma unroll
        for (int r = 0; r < 4; ++r){
          float v = fminf(fmaxf(hacc[r], -100.f), 100.f);      // hardtanh(+-100)
          const int m = mt*16 + quad*4 + r;
          ostS[m*64 + t*4 + s] = v;
          ApS[(mt*9+8)*512 + (m&15)*8 + s] = f2bf(v);          // x_sp(t+1) feedback
        }
      }
    }
    __syncthreads();
  }
  // ---- decoder epilogue: head_cr(15) ----
  if (w >= 4 && w < 6){
    const int mt = w - 4;
    f32x4 hacc = (f32x4){0.f,0.f,0.f,0.f};
    #pragma unroll
    for (int kt = 0; kt < 9; ++kt){
      bf16x8 a  = *(const bf16x8*)&aP[(mt*9+kt)*512];
      bf16x8 bv = *(const bf16x8*)&headcr[((size_t)kt*64 + lane)*8];
      hacc = __builtin_amdgcn_mfma_f32_16x16x32_bf16(a, bv, hacc, 0, 0, 0);
    }
    const int s = col16;
    if (s >= 4 && s < 6){
      #pragma unroll
      for (int r = 0; r < 4; ++r){
        float v = fmaxf(hacc[r], 0.f);
        const float o = __shfl_xor(v, 1, 64);
        const int m = mt*16 + quad*4 + r;
        const float mx = fmaxf(v, o);
        const float e0 = __expf(v-mx), e1 = __expf(o-mx);
        ostC[m*32 + 15*2 + (s-4)] = e0*rcp_(e0+e1);
      }
    }
  }
  __syncthreads();

  // ---- coalesced output flush (non-temporal stores) ----
  for (int i = tid; i < 2048; i += 512){
    const int oi = (brow0 + (i>>6))*64 + (i&63);
    const float v = ostS[i];
    if (f32) __builtin_nontemporal_store(v, outf + oi);
    else     __builtin_nontemporal_store(f2bf(v), outu + oi);
  }
  for (int i = tid; i < 1024; i += 512){
    const int oi = 1048576 + (brow0 + (i>>5))*32 + (i&31);
    const float v = ostC[i];
    if (f32) __builtin_nontemporal_store(v, outf + oi);
    else     __builtin_nontemporal_store(f2bf(v), outu + oi);
  }
}

extern "C" void kernel_launch(void* const* d_in, const int* in_sizes, int n_in,
                              void* d_out, int out_size, void* d_ws, size_t ws_size,
                              hipStream_t stream) {
  PackArgs pa;
  pa.wih[0]=(const ushort_t*)d_in[2];  pa.whh[0]=(const ushort_t*)d_in[3];
  pa.bih[0]=(const ushort_t*)d_in[4];  pa.bhh[0]=(const ushort_t*)d_in[5];
  pa.wih[1]=(const ushort_t*)d_in[6];  pa.whh[1]=(const ushort_t*)d_in[7];
  pa.bih[1]=(const ushort_t*)d_in[8];  pa.bhh[1]=(const ushort_t*)d_in[9];
  pa.wih[2]=(const ushort_t*)d_in[10]; pa.whh[2]=(const ushort_t*)d_in[11];
  pa.bih[2]=(const ushort_t*)d_in[12]; pa.bhh[2]=(const ushort_t*)d_in[13];
  pa.wih[3]=(const ushort_t*)d_in[14]; pa.whh[3]=(const ushort_t*)d_in[15];
  pa.bih[3]=(const ushort_t*)d_in[16]; pa.bhh[3]=(const ushort_t*)d_in[17];
  pa.fcsp_w=(const ushort_t*)d_in[18]; pa.fcsp_b=(const ushort_t*)d_in[19];
  pa.fccr_w=(const ushort_t*)d_in[20]; pa.fccr_b=(const ushort_t*)d_in[21];
  pa.emb_w =(const ushort_t*)d_in[22]; pa.emb_b =(const ushort_t*)d_in[23];
  pa.ws = (ushort_t*)d_ws;

  hipLaunchKernelGGL(pack_kernel, dim3((PACK_TOTAL + 255)/256), dim3(256), 0, stream, pa);
  hipLaunchKernelGGL(pvlstm_main, dim3(512), dim3(512), 0, stream,
      (const ushort_t*)d_ws,
      (const ushort_t*)d_in[0], (const ushort_t*)d_in[1],
      d_out);
}